// Round 15
// baseline (147.074 us; speedup 1.0000x reference)
//
#include <hip/hip_runtime.h>
#include <hip/hip_bf16.h>
#include <cmath>

using f32x4 = __attribute__((ext_vector_type(4))) float;
using s16x8 = __attribute__((ext_vector_type(8))) short;

__device__ __forceinline__ unsigned short f2bf(float f){
  union { float f; unsigned int i; } v; v.f = f;
  return (unsigned short)((v.i + 0x7FFFu + ((v.i >> 16) & 1u)) >> 16);
}

#define GLDS16(g, l) __builtin_amdgcn_global_load_lds( \
    (const __attribute__((address_space(1))) unsigned int*)(g), \
    (__attribute__((address_space(3))) unsigned int*)(l), 16, 0, 0)

// ---------------- prep: bf16 conversions + cls passthrough + tokensb pad ----------------
__global__ void k_prep(const float* __restrict__ Wd, const float* __restrict__ Wu,
                       const float* __restrict__ Wt, const float* __restrict__ Wf,
                       const float* __restrict__ Ap, const float* __restrict__ Bp,
                       const int* __restrict__ layerp, const float* __restrict__ x,
                       float* __restrict__ out,
                       unsigned short* __restrict__ Wdb, unsigned short* __restrict__ Wub,
                       unsigned short* __restrict__ Wtb, unsigned short* __restrict__ WB,
                       unsigned short* __restrict__ Ab, unsigned short* __restrict__ Blb,
                       unsigned short* __restrict__ tokensb){
  int idx = blockIdx.x * 256 + threadIdx.x;
  switch (blockIdx.y){
    case 0: if (idx < 24576)  Wdb[idx] = f2bf(Wd[idx]); break;
    case 1: if (idx < 73728)  Wub[idx] = f2bf(Wu[idx]); break;
    case 2: if (idx < 589824) Wtb[idx] = f2bf(Wt[idx]); break;
    case 3: if (idx < 688128){
      int n = idx / 896, c = idx - n * 896;
      WB[idx] = (c < 768) ? f2bf(Wf[n * 768 + c]) : (unsigned short)0;
    } break;
    case 4: if (idx < 28672){
      int r = idx >> 8;
      Ab[idx] = (r < 100) ? f2bf(Ap[idx]) : (unsigned short)0;
    } break;
    case 5: if (idx < 65536) Blb[idx] = f2bf(Bp[(long)(*layerp) * 65536 + idx]); break;
    case 6: if (idx < 24576) out[idx] = x[idx]; break;            // cls passthrough
    case 7: if (idx < 12288) tokensb[86016 + idx] = 0; break;     // pad rows 112..127
  }
}

// ---------------- 2-wave split-K MFMA mini-GEMM: out = epi(A @ B^T + bias) ----------------
template<int EPI>
__global__ __launch_bounds__(128) void k_mm(const unsigned short* __restrict__ A, int lda,
    const unsigned short* __restrict__ B, int ldb, int K,
    const float* __restrict__ bias, unsigned short* __restrict__ out, int ldo){
  __shared__ float lacc[16 * 17];
  int tid = threadIdx.x, w = tid >> 6, l = tid & 63;
  int l15 = l & 15, lhi = l >> 4;
  int m0 = blockIdx.x * 16, n0 = blockIdx.y * 16;
  f32x4 acc = (f32x4)0.0f;
  int nsteps = K >> 5;
  for (int s = w; s < nsteps; s += 2){
    int k0 = s * 32;
    s16x8 a = *(const s16x8*)(A + (long)(m0 + l15) * lda + k0 + lhi * 8);
    s16x8 b = *(const s16x8*)(B + (long)(n0 + l15) * ldb + k0 + lhi * 8);
    acc = __builtin_amdgcn_mfma_f32_16x16x32_bf16(a, b, acc, 0, 0, 0);
  }
  if (w == 1){
    #pragma unroll
    for (int r = 0; r < 4; r++) lacc[(lhi * 4 + r) * 17 + l15] = acc[r];
  }
  __syncthreads();
  if (w == 0){
    int col = n0 + l15;
    float bv = bias ? bias[col] : 0.0f;
    #pragma unroll
    for (int r = 0; r < 4; r++){
      int row = m0 + lhi * 4 + r;
      float v = acc[r] + lacc[(lhi * 4 + r) * 17 + l15] + bv;
      if (EPI == 0){
        v = 0.5f * v * (1.0f + erff(v * 0.70710678118654752f));
        out[(long)row * ldo + col] = f2bf(v);
      } else if (EPI == 1){
        out[(long)col * ldo + row] = f2bf(v);
      } else if (EPI == 2){
        out[(long)row * ldo + col] = f2bf(v);
      } else {
        out[(long)col * 896 + 768 + row] = (row < 100) ? f2bf(v) : (unsigned short)0;
      }
    }
  }
}

// ---------------- fused attn + big GEMM ----------------
// Block = 64 output rows, grid 512 = 8 XCD x 64 (2 exact rounds at 1 block/CU).
// LDS 160KB: A panel [64][768] bf16 (98,304 B) staged ONCE from xf (cvt+swizzle);
// P [64][128] bf16 (16,384 B); B/Ts dbuf region (49,152 B).
// Phase1: 12 chunks {A-chunk cvt->LDS; tokensb tile gl_lds dbuf; QK^T} -> softmax -> P.
// Phase2: nt=0..3 x t=0..13 {B dbuf; MFMA from A/P panel}; direct f32 epilogue.
__global__ __launch_bounds__(256, 1) void k_fused(const float* __restrict__ xf,
    const unsigned short* __restrict__ tokensb, const unsigned short* __restrict__ WB,
    const float* __restrict__ bfv, const float* __restrict__ scalep,
    float* __restrict__ outf){
  extern __shared__ __align__(16) unsigned short lds[];
  unsigned short* A_lds = lds;            // [64][768] us
  unsigned short* P_lds = lds + 49152;    // [64][128] us
  unsigned short* B_lds = lds + 57344;    // 2 x 12288 us (phase1: Ts 2 x 8192 us)

  int bid = blockIdx.x;                   // 512 = 8 XCD * 64
  int sid = (bid & 7) * 64 + (bid >> 3);
  long R0 = (long)sid * 64;
  int tid = threadIdx.x, w = tid >> 6, l = tid & 63;
  int l15 = l & 15, lhi = l >> 4;
  int lrow = l >> 3, lc = l & 7;
  int lsw = (lc ^ lrow) * 8;              // pre-swizzled source col (us)
  int wm = w >> 1, wn = w & 1;
  int rowA = tid >> 3, lcA = tid & 7;     // A-staging: rows rowA, rowA+32
  int keyA = rowA & 7;                    // (rowA+32)&7 == rowA&7

  // ================= phase 1: QK^T + softmax =================
  f32x4 aq[7];
  #pragma unroll
  for (int nf = 0; nf < 7; nf++) aq[nf] = (f32x4)0.0f;

  // prologue: Ts(0)
  #pragma unroll
  for (int i = 0; i < 4; i++){
    int idx = w * 4 + i, g = idx * 8 + lrow;
    GLDS16(tokensb + (long)g * 768 + lsw, B_lds + idx * 512);
  }

  for (int t = 0; t < 12; t++){
    // A chunk t: coalesced f32 -> cvt -> swizzled ds_write
    {
      const float* g0 = xf + (R0 + rowA) * 768 + t * 64 + lcA * 8;
      const float* g1 = xf + (R0 + rowA + 32) * 768 + t * 64 + lcA * 8;
      f32x4 a0 = *(const f32x4*)g0, a1 = *(const f32x4*)(g0 + 4);
      f32x4 b0 = *(const f32x4*)g1, b1 = *(const f32x4*)(g1 + 4);
      s16x8 c0, c1;
      #pragma unroll
      for (int j = 0; j < 4; j++){
        c0[j] = (short)f2bf(a0[j]); c0[4 + j] = (short)f2bf(a1[j]);
        c1[j] = (short)f2bf(b0[j]); c1[4 + j] = (short)f2bf(b1[j]);
      }
      *(s16x8*)(A_lds + rowA * 768 + t * 64 + ((lcA ^ keyA) << 3)) = c0;
      *(s16x8*)(A_lds + (rowA + 32) * 768 + t * 64 + ((lcA ^ keyA) << 3)) = c1;
    }
    asm volatile("s_waitcnt vmcnt(0) lgkmcnt(0)" ::: "memory");
    __builtin_amdgcn_s_barrier();
    if (t < 11){
      #pragma unroll
      for (int i = 0; i < 4; i++){
        int idx = w * 4 + i, g = idx * 8 + lrow;
        GLDS16(tokensb + (long)g * 768 + (t + 1) * 64 + lsw,
               B_lds + ((t + 1) & 1) * 8192 + idx * 512);
      }
    }
    const unsigned short* Ts = B_lds + (t & 1) * 8192;
    #pragma unroll
    for (int kk = 0; kk < 2; kk++){
      int xo = (kk * 64 + lhi * 16) ^ ((l15 & 7) << 4);
      s16x8 a = *(const s16x8*)(A_lds + (w * 16 + l15) * 768 + t * 64 + (xo >> 1));
      __builtin_amdgcn_s_setprio(1);
      #pragma unroll
      for (int nf = 0; nf < 7; nf++){
        s16x8 b = *(const s16x8*)(Ts + (nf * 16 + l15) * 64 + (xo >> 1));
        aq[nf] = __builtin_amdgcn_mfma_f32_16x16x32_bf16(a, b, aq[nf], 0, 0, 0);
      }
      __builtin_amdgcn_s_setprio(0);
    }
  }

  // softmax (wave w owns rows w*16..+16) -> P_lds (swizzled, cols 100..127 zero)
  {
    const float sc = 0.03608439182435161f; // 768^-0.5
    #pragma unroll
    for (int r = 0; r < 4; r++){
      float mx = -1e30f;
      #pragma unroll
      for (int nf = 0; nf < 7; nf++){
        int col = nf * 16 + l15;
        float v = aq[nf][r] * sc;
        if (col < 100 && v > mx) mx = v;
      }
      mx = fmaxf(mx, __shfl_xor(mx, 1));
      mx = fmaxf(mx, __shfl_xor(mx, 2));
      mx = fmaxf(mx, __shfl_xor(mx, 4));
      mx = fmaxf(mx, __shfl_xor(mx, 8));
      float p[7], sm = 0.f;
      #pragma unroll
      for (int nf = 0; nf < 7; nf++){
        int col = nf * 16 + l15;
        float v = (col < 100) ? __expf(aq[nf][r] * sc - mx) : 0.f;
        p[nf] = v; sm += v;
      }
      sm += __shfl_xor(sm, 1);
      sm += __shfl_xor(sm, 2);
      sm += __shfl_xor(sm, 4);
      sm += __shfl_xor(sm, 8);
      float inv = 1.f / sm;
      int rowl = w * 16 + lhi * 4 + r, rk = rowl & 7;
      #pragma unroll
      for (int nf = 0; nf < 7; nf++){
        int col = nf * 16 + l15;
        P_lds[rowl * 128 + (((col >> 3) ^ rk) << 3) + (col & 7)] = f2bf(p[nf] * inv);
      }
      int col = 112 + l15;
      P_lds[rowl * 128 + (((col >> 3) ^ rk) << 3) + (col & 7)] = 0;
    }
  }

  // ================= phase 2: out = xf + scale*([A|P] @ WB^T + bf) =================
  // prologue B(nt=0, t=0) into buf0 (overwrites Ts buf0; QKT(11) read buf1 - safe)
  #define BSTAGE(BUF, NT, T) { \
    _Pragma("unroll") \
    for (int ii = 0; ii < 6; ii++){ \
      int r = ii * 32 + w * 8 + lrow; \
      GLDS16(WB + (long)((NT) * 192 + r) * 896 + (T) * 64 + lsw, \
             B_lds + (BUF) * 12288 + (ii * 32 + w * 8) * 64); \
    } }
  BSTAGE(0, 0, 0);
  asm volatile("s_waitcnt lgkmcnt(0)" ::: "memory");   // P writes drained pre-barrier

  float scale = *scalep;
  for (int nt = 0; nt < 4; nt++){
    f32x4 acc[2][6];
    #pragma unroll
    for (int m = 0; m < 2; m++)
      #pragma unroll
      for (int n = 0; n < 6; n++) acc[m][n] = (f32x4)0.0f;

    for (int t = 0; t < 14; t++){
      asm volatile("s_waitcnt vmcnt(0)" ::: "memory");  // B(t) landed
      __builtin_amdgcn_s_barrier();                      // P visible / buf safe
      int t2 = t + 1, nt2 = nt;
      if (t2 == 14){ t2 = 0; nt2 = nt + 1; }
      if (nt2 < 4) BSTAGE(t2 & 1, nt2, t2);
      const unsigned short* Bb = B_lds + (t & 1) * 12288;
      #pragma unroll
      for (int ks = 0; ks < 2; ks++){
        s16x8 bk[6], af[2];
        #pragma unroll
        for (int n = 0; n < 6; n++){
          int br = wn * 96 + n * 16 + l15;
          int xo = (ks * 64 + lhi * 16) ^ ((br & 7) << 4);
          bk[n] = *(const s16x8*)(Bb + br * 64 + (xo >> 1));
        }
        #pragma unroll
        for (int m = 0; m < 2; m++){
          int ar = wm * 32 + m * 16 + l15;
          int xo = (ks * 64 + lhi * 16) ^ ((ar & 7) << 4);
          af[m] = (t < 12)
            ? *(const s16x8*)(A_lds + ar * 768 + t * 64 + (xo >> 1))
            : *(const s16x8*)(P_lds + ar * 128 + (t - 12) * 64 + (xo >> 1));
        }
        __builtin_amdgcn_s_setprio(1);
        #pragma unroll
        for (int m = 0; m < 2; m++)
          #pragma unroll
          for (int n = 0; n < 6; n++)
            acc[m][n] = __builtin_amdgcn_mfma_f32_16x16x32_bf16(af[m], bk[n], acc[m][n], 0, 0, 0);
        __builtin_amdgcn_s_setprio(0);
      }
    }
    // epilogue nt: direct stores (16-lane 64B segments), residual from f32 xf (L2-hot)
    #pragma unroll
    for (int m = 0; m < 2; m++)
      #pragma unroll
      for (int n = 0; n < 6; n++){
        int gcol = nt * 192 + wn * 96 + n * 16 + l15;
        float bias = bfv[gcol];
        #pragma unroll
        for (int r = 0; r < 4; r++){
          long grow = R0 + wm * 32 + m * 16 + lhi * 4 + r;
          outf[grow * 768 + gcol] = xf[grow * 768 + gcol] + scale * (acc[m][n][r] + bias);
        }
      }
  }
  #undef BSTAGE
}

extern "C" void kernel_launch(void* const* d_in, const int* in_sizes, int n_in,
                              void* d_out, int out_size, void* d_ws, size_t ws_size,
                              hipStream_t stream) {
  const float* x   = (const float*)d_in[0];
  const float* Wd  = (const float*)d_in[1];
  const float* bd  = (const float*)d_in[2];
  const float* Wu  = (const float*)d_in[3];
  const float* bu  = (const float*)d_in[4];
  const float* Wt  = (const float*)d_in[5];
  const float* bt  = (const float*)d_in[6];
  const float* Wf  = (const float*)d_in[7];
  const float* bfv = (const float*)d_in[8];
  const float* Ap  = (const float*)d_in[9];
  const float* Bp  = (const float*)d_in[10];
  const float* scalep = (const float*)d_in[11];
  const int* layerp   = (const int*)d_in[12];
  float* out = (float*)d_out;

  char* ws = (char*)d_ws;
  unsigned short* WB      = (unsigned short*)(ws);              // 1,376,256 (768 x 896)
  unsigned short* Wtb     = (unsigned short*)(ws + 1376256);    // 1,179,648 (768 x 768)
  unsigned short* tokensb = (unsigned short*)(ws + 2555904);    //   196,608 (128 x 768, padded)
  unsigned short* t2fb    = (unsigned short*)(ws + 2752512);    //   172,032 (112 x 768)
  unsigned short* Ab      = (unsigned short*)(ws + 2924544);    //    57,344 (112 x 256)
  unsigned short* Blb     = (unsigned short*)(ws + 2981888);    //   131,072 (256 x 256)
  unsigned short* Wdb     = (unsigned short*)(ws + 3112960);    //    49,152 ( 96 x 256)
  unsigned short* Wub     = (unsigned short*)(ws + 3162112);    //   147,456 (768 x  96)
  unsigned short* hb      = (unsigned short*)(ws + 3309568);    //    49,152 (256 x  96)
  unsigned short* Bfmt    = (unsigned short*)(ws + 3358720);    //   393,216 (768 x 256, Bf^T)

  const float* xf = x + 32 * 768;   // feats (skip cls rows)
  float* outf = out + 32 * 768;

  static int lds_attr_set = 0;
  if (!lds_attr_set){
    hipFuncSetAttribute((const void*)k_fused, hipFuncAttributeMaxDynamicSharedMemorySize, 163840);
    lds_attr_set = 1;
  }

  k_prep<<<dim3(2688, 8), 256, 0, stream>>>(Wd, Wu, Wt, Wf, Ap, Bp, layerp, x, out,
                                            Wdb, Wub, Wtb, WB, Ab, Blb, tokensb);
  k_mm<0><<<dim3(16, 6),  128, 0, stream>>>(Blb, 256, Wdb, 256, 256, bd, hb, 96);
  k_mm<1><<<dim3(16, 48), 128, 0, stream>>>(hb, 96, Wub, 96, 96, bu, Bfmt, 256);
  k_mm<2><<<dim3(7, 48),  128, 0, stream>>>(Ab, 256, Bfmt, 256, 256, nullptr, tokensb, 768);
  k_mm<2><<<dim3(7, 48),  128, 0, stream>>>(tokensb, 768, Wtb, 768, 768, bt, t2fb, 768);
  k_mm<3><<<dim3(7, 48),  128, 0, stream>>>(t2fb, 768, WB, 896, 768, nullptr, WB, 0);

  k_fused<<<512, 256, 163840, stream>>>(xf, tokensb, WB, bfv, scalep, outf);
}

// Round 16
// 143.997 us; speedup vs baseline: 1.0214x; 1.0214x over previous
//
#include <hip/hip_runtime.h>
#include <hip/hip_bf16.h>
#include <cmath>

using f32x4 = __attribute__((ext_vector_type(4))) float;
using s16x8 = __attribute__((ext_vector_type(8))) short;

__device__ __forceinline__ unsigned short f2bf(float f){
  union { float f; unsigned int i; } v; v.f = f;
  return (unsigned short)((v.i + 0x7FFFu + ((v.i >> 16) & 1u)) >> 16);
}

#define GLDS16(g, l) __builtin_amdgcn_global_load_lds( \
    (const __attribute__((address_space(1))) unsigned int*)(g), \
    (__attribute__((address_space(3))) unsigned int*)(l), 16, 0, 0)

// ---------------- prep: bf16 conversions + cls passthrough + tokensb pad ----------------
__global__ void k_prep(const float* __restrict__ Wd, const float* __restrict__ Wu,
                       const float* __restrict__ Wt, const float* __restrict__ Wf,
                       const float* __restrict__ Ap, const float* __restrict__ Bp,
                       const int* __restrict__ layerp, const float* __restrict__ x,
                       float* __restrict__ out,
                       unsigned short* __restrict__ Wdb, unsigned short* __restrict__ Wub,
                       unsigned short* __restrict__ Wtb, unsigned short* __restrict__ WB,
                       unsigned short* __restrict__ Ab, unsigned short* __restrict__ Blb,
                       unsigned short* __restrict__ tokensb){
  int idx = blockIdx.x * 256 + threadIdx.x;
  switch (blockIdx.y){
    case 0: if (idx < 24576)  Wdb[idx] = f2bf(Wd[idx]); break;
    case 1: if (idx < 73728)  Wub[idx] = f2bf(Wu[idx]); break;
    case 2: if (idx < 589824) Wtb[idx] = f2bf(Wt[idx]); break;
    case 3: if (idx < 688128){
      int n = idx / 896, c = idx - n * 896;
      WB[idx] = (c < 768) ? f2bf(Wf[n * 768 + c]) : (unsigned short)0;
    } break;
    case 4: if (idx < 28672){
      int r = idx >> 8;
      Ab[idx] = (r < 100) ? f2bf(Ap[idx]) : (unsigned short)0;
    } break;
    case 5: if (idx < 65536) Blb[idx] = f2bf(Bp[(long)(*layerp) * 65536 + idx]); break;
    case 6: if (idx < 24576) out[idx] = x[idx]; break;            // cls passthrough
    case 7: if (idx < 12288) tokensb[86016 + idx] = 0; break;     // pad rows 112..127
  }
}

// ---------------- 2-wave split-K MFMA mini-GEMM: out = epi(A @ B^T + bias) ----------------
template<int EPI>
__global__ __launch_bounds__(128) void k_mm(const unsigned short* __restrict__ A, int lda,
    const unsigned short* __restrict__ B, int ldb, int K,
    const float* __restrict__ bias, unsigned short* __restrict__ out, int ldo){
  __shared__ float lacc[16 * 17];
  int tid = threadIdx.x, w = tid >> 6, l = tid & 63;
  int l15 = l & 15, lhi = l >> 4;
  int m0 = blockIdx.x * 16, n0 = blockIdx.y * 16;
  f32x4 acc = (f32x4)0.0f;
  int nsteps = K >> 5;
  for (int s = w; s < nsteps; s += 2){
    int k0 = s * 32;
    s16x8 a = *(const s16x8*)(A + (long)(m0 + l15) * lda + k0 + lhi * 8);
    s16x8 b = *(const s16x8*)(B + (long)(n0 + l15) * ldb + k0 + lhi * 8);
    acc = __builtin_amdgcn_mfma_f32_16x16x32_bf16(a, b, acc, 0, 0, 0);
  }
  if (w == 1){
    #pragma unroll
    for (int r = 0; r < 4; r++) lacc[(lhi * 4 + r) * 17 + l15] = acc[r];
  }
  __syncthreads();
  if (w == 0){
    int col = n0 + l15;
    float bv = bias ? bias[col] : 0.0f;
    #pragma unroll
    for (int r = 0; r < 4; r++){
      int row = m0 + lhi * 4 + r;
      float v = acc[r] + lacc[(lhi * 4 + r) * 17 + l15] + bv;
      if (EPI == 0){
        v = 0.5f * v * (1.0f + erff(v * 0.70710678118654752f));
        out[(long)row * ldo + col] = f2bf(v);
      } else if (EPI == 1){
        out[(long)col * ldo + row] = f2bf(v);
      } else if (EPI == 2){
        out[(long)row * ldo + col] = f2bf(v);
      } else {
        out[(long)col * 896 + 768 + row] = (row < 100) ? f2bf(v) : (unsigned short)0;
      }
    }
  }
}

// ---------------- fused attn + big GEMM, 2 blocks/CU ----------------
// Block = 64 rows, 4 waves; wave w owns rows w*16..+16. Grid 512 = 8 XCD x 64
// (exactly 1 round at 2 blocks/CU). LDS 72KB: A-chunk 8KB + P 16KB + B dbuf 48KB.
// A panel lives in REGISTERS: afr[24] per lane (96 VGPR), filled chunk-by-chunk in
// phase 1 (coalesced f32 -> cvt -> swizzled LDS -> frag read) fused with QK^T.
// Phase 2: nt=0..3, t unrolled 0..13; B dbuf counted vmcnt(6); A from regs / P-LDS.
__global__ __launch_bounds__(256, 2) void k_fused(const float* __restrict__ xf,
    const unsigned short* __restrict__ tokensb, const unsigned short* __restrict__ WB,
    const float* __restrict__ bfv, const float* __restrict__ scalep,
    float* __restrict__ outf){
  extern __shared__ __align__(16) unsigned short lds[];
  unsigned short* A_tile = lds;            // [64][64] us = 8 KB (phase 1 only)
  unsigned short* P_lds  = lds + 4096;     // [64][128] us = 16 KB
  unsigned short* B_lds  = lds + 12288;    // 2 x 12288 us = 48 KB (phase1: Ts 2x8192 us)

  int bid = blockIdx.x;                    // 512 = 8 XCD * 64
  int sid = (bid & 7) * 64 + (bid >> 3);
  long R0 = (long)sid * 64;
  int tid = threadIdx.x, w = tid >> 6, l = tid & 63;
  int l15 = l & 15, lhi = l >> 4;
  int lrow = l >> 3, lc = l & 7;
  int lsw = (lc ^ lrow) * 8;               // pre-swizzled source col (us)
  int rowA = tid >> 3, lcA = tid & 7;      // A-staging rows rowA, rowA+32
  int keyA = rowA & 7;

  s16x8 afr[24];                           // persistent A frags: afr[t*2+ks]
  f32x4 aq[7];
  #pragma unroll
  for (int nf = 0; nf < 7; nf++) aq[nf] = (f32x4)0.0f;

  // ================= phase 1: stage A to regs + QK^T =================
  #pragma unroll
  for (int i = 0; i < 4; i++){             // Ts(0) prologue
    int idx = w * 4 + i, g = idx * 8 + lrow;
    GLDS16(tokensb + (long)g * 768 + lsw, B_lds + idx * 512);
  }

  #pragma unroll
  for (int t = 0; t < 12; t++){
    // A chunk t: coalesced f32 -> cvt -> swizzled ds_write into A_tile
    {
      const float* g0 = xf + (R0 + rowA) * 768 + t * 64 + lcA * 8;
      const float* g1 = xf + (R0 + rowA + 32) * 768 + t * 64 + lcA * 8;
      f32x4 a0 = *(const f32x4*)g0, a1 = *(const f32x4*)(g0 + 4);
      f32x4 b0 = *(const f32x4*)g1, b1 = *(const f32x4*)(g1 + 4);
      s16x8 c0, c1;
      #pragma unroll
      for (int j = 0; j < 4; j++){
        c0[j] = (short)f2bf(a0[j]); c0[4 + j] = (short)f2bf(a1[j]);
        c1[j] = (short)f2bf(b0[j]); c1[4 + j] = (short)f2bf(b1[j]);
      }
      *(s16x8*)(A_tile + rowA * 64 + ((lcA ^ keyA) << 3)) = c0;
      *(s16x8*)(A_tile + (rowA + 32) * 64 + ((lcA ^ keyA) << 3)) = c1;
    }
    asm volatile("s_waitcnt vmcnt(0) lgkmcnt(0)" ::: "memory");  // Ts(t) + A writes done
    __builtin_amdgcn_s_barrier();
    if (t < 11){
      #pragma unroll
      for (int i = 0; i < 4; i++){
        int idx = w * 4 + i, g = idx * 8 + lrow;
        GLDS16(tokensb + (long)g * 768 + (t + 1) * 64 + lsw,
               B_lds + ((t + 1) & 1) * 8192 + idx * 512);
      }
    }
    // read this wave's A frags into registers (kept for phase 2)
    #pragma unroll
    for (int ks = 0; ks < 2; ks++){
      int xo = (ks * 64 + lhi * 16) ^ ((l15 & 7) << 4);
      afr[t * 2 + ks] = *(const s16x8*)(A_tile + (w * 16 + l15) * 64 + (xo >> 1));
    }
    const unsigned short* Ts = B_lds + (t & 1) * 8192;
    #pragma unroll
    for (int ks = 0; ks < 2; ks++){
      int xo = (ks * 64 + lhi * 16) ^ ((l15 & 7) << 4);
      __builtin_amdgcn_s_setprio(1);
      #pragma unroll
      for (int nf = 0; nf < 7; nf++){
        s16x8 b = *(const s16x8*)(Ts + (nf * 16 + l15) * 64 + (xo >> 1));
        aq[nf] = __builtin_amdgcn_mfma_f32_16x16x32_bf16(afr[t * 2 + ks], b, aq[nf], 0, 0, 0);
      }
      __builtin_amdgcn_s_setprio(0);
    }
    __builtin_amdgcn_s_barrier();   // protects A_tile overwrite + Ts buf reuse
  }

  // softmax (wave w owns rows w*16..) -> P_lds (swizzled, cols 100..127 zero)
  {
    const float sc = 0.03608439182435161f; // 768^-0.5
    #pragma unroll
    for (int r = 0; r < 4; r++){
      float mx = -1e30f;
      #pragma unroll
      for (int nf = 0; nf < 7; nf++){
        int col = nf * 16 + l15;
        float v = aq[nf][r] * sc;
        if (col < 100 && v > mx) mx = v;
      }
      mx = fmaxf(mx, __shfl_xor(mx, 1));
      mx = fmaxf(mx, __shfl_xor(mx, 2));
      mx = fmaxf(mx, __shfl_xor(mx, 4));
      mx = fmaxf(mx, __shfl_xor(mx, 8));
      float p[7], sm = 0.f;
      #pragma unroll
      for (int nf = 0; nf < 7; nf++){
        int col = nf * 16 + l15;
        float v = (col < 100) ? __expf(aq[nf][r] * sc - mx) : 0.f;
        p[nf] = v; sm += v;
      }
      sm += __shfl_xor(sm, 1);
      sm += __shfl_xor(sm, 2);
      sm += __shfl_xor(sm, 4);
      sm += __shfl_xor(sm, 8);
      float inv = 1.f / sm;
      int rowl = w * 16 + lhi * 4 + r, rk = rowl & 7;
      #pragma unroll
      for (int nf = 0; nf < 7; nf++){
        int col = nf * 16 + l15;
        P_lds[rowl * 128 + (((col >> 3) ^ rk) << 3) + (col & 7)] = f2bf(p[nf] * inv);
      }
      int col = 112 + l15;
      P_lds[rowl * 128 + (((col >> 3) ^ rk) << 3) + (col & 7)] = 0;
    }
  }
  asm volatile("s_waitcnt lgkmcnt(0)" ::: "memory");
  __builtin_amdgcn_s_barrier();    // P visible; Ts region free for B

  // ================= phase 2: out = xf + scale*([A|P] @ WB^T + bf) =================
  #define BSTAGE(BUF, NT, T) { \
    _Pragma("unroll") \
    for (int ii = 0; ii < 6; ii++){ \
      int r = ii * 32 + w * 8 + lrow; \
      GLDS16(WB + (long)((NT) * 192 + r) * 896 + (T) * 64 + lsw, \
             B_lds + (BUF) * 12288 + (ii * 32 + w * 8) * 64); \
    } }
  BSTAGE(0, 0, 0);

  float scale = *scalep;
  for (int nt = 0; nt < 4; nt++){
    f32x4 acc[12];
    #pragma unroll
    for (int n = 0; n < 12; n++) acc[n] = (f32x4)0.0f;

    #pragma unroll
    for (int t = 0; t < 14; t++){
      int t2 = t + 1, nt2 = nt;
      if (t2 == 14){ t2 = 0; nt2 = nt + 1; }
      if (nt2 < 4){
        BSTAGE(t2 & 1, nt2, t2);
        asm volatile("s_waitcnt vmcnt(6)" ::: "memory");   // B(t) landed; B(t+1) in flight
      } else {
        asm volatile("s_waitcnt vmcnt(0)" ::: "memory");
      }
      __builtin_amdgcn_s_barrier();
      const unsigned short* Bb = B_lds + (t & 1) * 12288;
      #pragma unroll
      for (int ks = 0; ks < 2; ks++){
        s16x8 aF;
        if (t < 12){
          aF = afr[t * 2 + ks];
        } else {
          int xo = (ks * 64 + lhi * 16) ^ ((l15 & 7) << 4);
          aF = *(const s16x8*)(P_lds + (w * 16 + l15) * 128 + (t - 12) * 64 + (xo >> 1));
        }
        __builtin_amdgcn_s_setprio(1);
        #pragma unroll
        for (int n = 0; n < 12; n++){
          int br = n * 16 + l15;
          int xo = (ks * 64 + lhi * 16) ^ ((br & 7) << 4);
          s16x8 b = *(const s16x8*)(Bb + br * 64 + (xo >> 1));
          acc[n] = __builtin_amdgcn_mfma_f32_16x16x32_bf16(aF, b, acc[n], 0, 0, 0);
        }
        __builtin_amdgcn_s_setprio(0);
      }
    }
    // epilogue nt: 4x64B-segment stores; residual from f32 xf (L2/L3-hot)
    #pragma unroll
    for (int n = 0; n < 12; n++){
      int gcol = nt * 192 + n * 16 + l15;
      float bias = bfv[gcol];
      #pragma unroll
      for (int r = 0; r < 4; r++){
        long grow = R0 + w * 16 + lhi * 4 + r;
        outf[grow * 768 + gcol] = xf[grow * 768 + gcol] + scale * (acc[n][r] + bias);
      }
    }
  }
  #undef BSTAGE
}

extern "C" void kernel_launch(void* const* d_in, const int* in_sizes, int n_in,
                              void* d_out, int out_size, void* d_ws, size_t ws_size,
                              hipStream_t stream) {
  const float* x   = (const float*)d_in[0];
  const float* Wd  = (const float*)d_in[1];
  const float* bd  = (const float*)d_in[2];
  const float* Wu  = (const float*)d_in[3];
  const float* bu  = (const float*)d_in[4];
  const float* Wt  = (const float*)d_in[5];
  const float* bt  = (const float*)d_in[6];
  const float* Wf  = (const float*)d_in[7];
  const float* bfv = (const float*)d_in[8];
  const float* Ap  = (const float*)d_in[9];
  const float* Bp  = (const float*)d_in[10];
  const float* scalep = (const float*)d_in[11];
  const int* layerp   = (const int*)d_in[12];
  float* out = (float*)d_out;

  char* ws = (char*)d_ws;
  unsigned short* WB      = (unsigned short*)(ws);              // 1,376,256 (768 x 896)
  unsigned short* Wtb     = (unsigned short*)(ws + 1376256);    // 1,179,648 (768 x 768)
  unsigned short* tokensb = (unsigned short*)(ws + 2555904);    //   196,608 (128 x 768, padded)
  unsigned short* t2fb    = (unsigned short*)(ws + 2752512);    //   172,032 (112 x 768)
  unsigned short* Ab      = (unsigned short*)(ws + 2924544);    //    57,344 (112 x 256)
  unsigned short* Blb     = (unsigned short*)(ws + 2981888);    //   131,072 (256 x 256)
  unsigned short* Wdb     = (unsigned short*)(ws + 3112960);    //    49,152 ( 96 x 256)
  unsigned short* Wub     = (unsigned short*)(ws + 3162112);    //   147,456 (768 x  96)
  unsigned short* hb      = (unsigned short*)(ws + 3309568);    //    49,152 (256 x  96)
  unsigned short* Bfmt    = (unsigned short*)(ws + 3358720);    //   393,216 (768 x 256, Bf^T)

  const float* xf = x + 32 * 768;   // feats (skip cls rows)
  float* outf = out + 32 * 768;

  static int lds_attr_set = 0;
  if (!lds_attr_set){
    hipFuncSetAttribute((const void*)k_fused, hipFuncAttributeMaxDynamicSharedMemorySize, 73728);
    lds_attr_set = 1;
  }

  k_prep<<<dim3(2688, 8), 256, 0, stream>>>(Wd, Wu, Wt, Wf, Ap, Bp, layerp, x, out,
                                            Wdb, Wub, Wtb, WB, Ab, Blb, tokensb);
  k_mm<0><<<dim3(16, 6),  128, 0, stream>>>(Blb, 256, Wdb, 256, 256, bd, hb, 96);
  k_mm<1><<<dim3(16, 48), 128, 0, stream>>>(hb, 96, Wub, 96, 96, bu, Bfmt, 256);
  k_mm<2><<<dim3(7, 48),  128, 0, stream>>>(Ab, 256, Bfmt, 256, 256, nullptr, tokensb, 768);
  k_mm<2><<<dim3(7, 48),  128, 0, stream>>>(tokensb, 768, Wtb, 768, 768, bt, t2fb, 768);
  k_mm<3><<<dim3(7, 48),  128, 0, stream>>>(t2fb, 768, WB, 896, 768, nullptr, WB, 0);

  k_fused<<<512, 256, 73728, stream>>>(xf, tokensb, WB, bfv, scalep, outf);
}